// Round 2
// baseline (193.982 us; speedup 1.0000x reference)
//
#include <hip/hip_runtime.h>
#include <stdint.h>

#define NROW 16384
#define DDIM 128
#define ROWB 256            // bytes per row of bf16 z

constexpr int TS    = 256;                      // square tile side
constexpr int NTILE = NROW / TS;                // 64
constexpr int NBLK  = NTILE * (NTILE + 1) / 2;  // 2080 upper-tri tiles
constexpr int NB    = 64;                       // cols per j-tile
constexpr int JT    = TS / NB;                  // 4 j-tiles per block

typedef __bf16 bf16x8 __attribute__((ext_vector_type(8)));
typedef float  f32x4  __attribute__((ext_vector_type(4)));
typedef int    i32x4  __attribute__((ext_vector_type(4)));

typedef const uint32_t __attribute__((address_space(1)))* gptr_t;
typedef uint32_t __attribute__((address_space(3)))*       lptr_t;

__device__ __forceinline__ unsigned short f2bf(float x) {
  union { float f; uint32_t u; } c; c.f = x;
  uint32_t u = c.u + 0x7fffu + ((c.u >> 16) & 1u);   // RNE
  return (unsigned short)(u >> 16);
}

// fp32 -> bf16 with the scale folded in: (1/T) * sqrt(log2(e)),
// so the MFMA accumulator equals a*log2(e), ready for v_exp_f32 (exp2).
__global__ __launch_bounds__(256) void prep_kernel(const float* __restrict__ z,
                                                   unsigned short* __restrict__ zs,
                                                   float* __restrict__ s) {
  const float SC = 12.011224087864498f;  // 10 * sqrt(1.4426950408889634)
  int t = blockIdx.x * 256 + threadIdx.x;
  float4 v = reinterpret_cast<const float4*>(z)[t];
  ushort4 o;
  o.x = f2bf(v.x * SC); o.y = f2bf(v.y * SC);
  o.z = f2bf(v.z * SC); o.w = f2bf(v.w * SC);
  reinterpret_cast<ushort4*>(zs)[t] = o;
  if (t < NROW) s[t] = 0.0f;             // rowsum accumulator (ws is poisoned)
}

// Upper-triangle 256x256 tiles: block (bi,bj), bi<=bj. Off-diagonal tiles
// contribute rowsums (rows of tile bi) AND colsums (== rowsums of tile bj
// by symmetry of exp(zs zs^T)). Diagonal: full tile, rowsums only.
__global__ __launch_bounds__(512, 4) void gemm_exp_kernel(const unsigned short* __restrict__ zs,
                                                          float* __restrict__ s) {
  __shared__ __align__(16) char smem[2 * NB * ROWB];   // 32 KB B double-buffer
  const int tid  = threadIdx.x;
  const int lane = tid & 63;
  const int wid  = tid >> 6;

  // linear block id -> (bi, bj) upper triangle, cum(i) = 64i - i(i-1)/2
  const int t = blockIdx.x;
#define CUM(i) (64 * (i) - ((i) * ((i) - 1)) / 2)
  int bi = (int)((129.0f - sqrtf((float)(16641 - 8 * t))) * 0.5f);
  while (CUM(bi + 1) <= t) ++bi;
  while (CUM(bi) > t) --bi;
  const int bj = bi + (t - CUM(bi));
  const bool isDiag = (bi == bj);
#undef CUM

  const int rowBase = bi * TS + wid * 32;   // this wave's 32 rows
  const int colBase = bj * TS;
  const char* zb = (const char*)zs;

  // A fragments: 16x16x32 A layout row=lane&15, k=(lane>>4)*8+e -> 16B/lane
  bf16x8 afrag[2][4];   // [mf][ks]
  {
    const int r0 = rowBase + (lane & 15);
    const int kb = (lane >> 4) << 4;
#pragma unroll
    for (int mf = 0; mf < 2; ++mf)
#pragma unroll
      for (int ks = 0; ks < 4; ++ks) {
        i32x4 raw = *reinterpret_cast<const i32x4*>(
            zb + (size_t)(r0 + mf * 16) * ROWB + ks * 64 + kb);
        afrag[mf][ks] = __builtin_bit_cast(bf16x8, raw);
      }
  }

  float rs[2][4];   // rowsum accumulators
  float cs[4][4];   // colsum accumulators [jt][nf] (jt loop fully unrolled)
#pragma unroll
  for (int mf = 0; mf < 2; ++mf)
#pragma unroll
    for (int r = 0; r < 4; ++r) rs[mf][r] = 0.0f;
#pragma unroll
  for (int a = 0; a < 4; ++a)
#pragma unroll
    for (int b = 0; b < 4; ++b) cs[a][b] = 0.0f;

  // Stage one 64x128 bf16 B-tile (16 KB): linear LDS dest + inverse-XOR-
  // swizzled global source; reads apply the same involution (rule #21).
#define STAGE_B(buf, jtile)                                                       \
  {                                                                               \
    _Pragma("unroll")                                                             \
    for (int i_ = 0; i_ < 2; ++i_) {                                              \
      const int destByte_ = i_ * 8192 + tid * 16;                                 \
      const int r_  = destByte_ >> 8;                                             \
      const int cb_ = destByte_ & 0xF0;                                           \
      const int srcByte_ = (colBase + (jtile) * NB + r_) * ROWB                   \
                           + (cb_ ^ ((r_ & 7) << 4));                             \
      __builtin_amdgcn_global_load_lds((gptr_t)(zb + srcByte_),                   \
          (lptr_t)(smem + (buf) * (NB * ROWB) + destByte_), 16, 0, 0);            \
    }                                                                             \
  }

  STAGE_B(0, 0);

#pragma unroll
  for (int jt = 0; jt < JT; ++jt) {
    const int cur = jt & 1;
    if (jt + 1 < JT) {
      STAGE_B(cur ^ 1, jt + 1);
      asm volatile("s_waitcnt vmcnt(2)" ::: "memory");  // current tile landed
    } else {
      asm volatile("s_waitcnt vmcnt(0)" ::: "memory");
    }
    __builtin_amdgcn_s_barrier();

    f32x4 acc[2][4];
#pragma unroll
    for (int mf = 0; mf < 2; ++mf)
#pragma unroll
      for (int nf = 0; nf < 4; ++nf) {
        f32x4 zv = {0.f, 0.f, 0.f, 0.f};
        acc[mf][nf] = zv;
      }

    const char* bufp = smem + cur * (NB * ROWB);
#pragma unroll
    for (int ks = 0; ks < 4; ++ks) {
      bf16x8 bfrag[4];
#pragma unroll
      for (int nf = 0; nf < 4; ++nf) {
        const int r   = nf * 16 + (lane & 15);
        const int kb  = ks * 64 + ((lane >> 4) << 4);
        const int off = r * ROWB + (kb ^ ((r & 7) << 4));
        i32x4 raw = *reinterpret_cast<const i32x4*>(bufp + off);
        bfrag[nf] = __builtin_bit_cast(bf16x8, raw);
      }
#pragma unroll
      for (int mf = 0; mf < 2; ++mf)
#pragma unroll
        for (int nf = 0; nf < 4; ++nf)
          acc[mf][nf] = __builtin_amdgcn_mfma_f32_16x16x32_bf16(
              afrag[mf][ks], bfrag[nf], acc[mf][nf], 0, 0, 0);
    }

    // acc holds a*log2(e) -> exp(a) = exp2(acc); feed row + col accumulators
#pragma unroll
    for (int mf = 0; mf < 2; ++mf)
#pragma unroll
      for (int nf = 0; nf < 4; ++nf) {
        f32x4 a4 = acc[mf][nf];
        float e0 = __builtin_amdgcn_exp2f(a4[0]);
        float e1 = __builtin_amdgcn_exp2f(a4[1]);
        float e2 = __builtin_amdgcn_exp2f(a4[2]);
        float e3 = __builtin_amdgcn_exp2f(a4[3]);
        rs[mf][0] += e0; rs[mf][1] += e1; rs[mf][2] += e2; rs[mf][3] += e3;
        cs[jt][nf] += (e0 + e1) + (e2 + e3);
      }

    __builtin_amdgcn_s_barrier();   // all waves done reading buf[cur]
  }
#undef STAGE_B

  // Rowsums: C/D layout col=lane&15, row=(lane>>4)*4+reg. Reduce the 16
  // column-lanes, one atomicAdd per row.
#pragma unroll
  for (int mf = 0; mf < 2; ++mf)
#pragma unroll
    for (int r = 0; r < 4; ++r) {
      float v = rs[mf][r];
      v += __shfl_xor(v, 1);
      v += __shfl_xor(v, 2);
      v += __shfl_xor(v, 4);
      v += __shfl_xor(v, 8);
      if ((lane & 15) == 0) {
        const int row = rowBase + mf * 16 + ((lane >> 4) << 2) + r;
        atomicAdd(&s[row], v);
      }
    }

  // Colsums (off-diagonal only): reduce lane-groups, stage per-wave partials
  // in the (now free) LDS buffer 0, combine, one atomic per column.
  if (!isDiag) {
    float* csm = (float*)smem;   // [8 waves][256 cols] = 8 KB, inside buf0
#pragma unroll
    for (int jt = 0; jt < 4; ++jt)
#pragma unroll
      for (int nf = 0; nf < 4; ++nf) {
        float v = cs[jt][nf];
        v += __shfl_xor(v, 16);
        v += __shfl_xor(v, 32);
        if (lane < 16) csm[wid * 256 + jt * 64 + nf * 16 + lane] = v;
      }
    __syncthreads();
    if (tid < 256) {
      float sum = 0.0f;
#pragma unroll
      for (int w = 0; w < 8; ++w) sum += csm[w * 256 + tid];
      atomicAdd(&s[colBase + tid], sum);
    }
  }
}

__global__ __launch_bounds__(1024) void reduce_kernel(const float* __restrict__ s,
                                                      float* __restrict__ out) {
  const int tid = threadIdx.x;
  float acc = 0.0f;
  for (int i = tid; i < NROW; i += 1024) acc += __log2f(s[i]);
#pragma unroll
  for (int m = 32; m >= 1; m >>= 1) acc += __shfl_xor(acc, m);
  __shared__ float wsum[16];
  if ((tid & 63) == 0) wsum[tid >> 6] = acc;
  __syncthreads();
  if (tid == 0) {
    float tot = 0.0f;
#pragma unroll
    for (int w = 0; w < 16; ++w) tot += wsum[w];
    // mean(-log(sum/N)) = log N - (ln2/N) * sum(log2 s_i)
    out[0] = logf((float)NROW) - 0.6931471805599453f * tot / (float)NROW;
  }
}

extern "C" void kernel_launch(void* const* d_in, const int* in_sizes, int n_in,
                              void* d_out, int out_size, void* d_ws, size_t ws_size,
                              hipStream_t stream) {
  const float* z = (const float*)d_in[0];
  unsigned short* zs = (unsigned short*)d_ws;                       // 4 MB bf16
  float* s = (float*)((char*)d_ws + (size_t)NROW * DDIM * 2);       // 64 KB rowsums
  float* out = (float*)d_out;

  prep_kernel<<<dim3(NROW * DDIM / 4 / 256), dim3(256), 0, stream>>>(z, zs, s);
  gemm_exp_kernel<<<dim3(NBLK), dim3(512), 0, stream>>>(zs, s);
  reduce_kernel<<<dim3(1), dim3(1024), 0, stream>>>(s, out);
}

// Round 3
// 162.968 us; speedup vs baseline: 1.1903x; 1.1903x over previous
//
#include <hip/hip_runtime.h>
#include <stdint.h>

#define NROW 16384
#define DDIM 128
#define ROWB 256            // bytes per row of bf16 z

constexpr int TS    = 256;                      // square tile side
constexpr int NTILE = NROW / TS;                // 64
constexpr int NBLK  = NTILE * (NTILE + 1) / 2;  // 2080 upper-tri tiles
constexpr int NB    = 64;                       // cols per j-tile
constexpr int JT    = TS / NB;                  // 4 j-tiles per block

typedef __bf16 bf16x8 __attribute__((ext_vector_type(8)));
typedef float  f32x4  __attribute__((ext_vector_type(4)));
typedef int    i32x4  __attribute__((ext_vector_type(4)));

typedef const uint32_t __attribute__((address_space(1)))* gptr_t;
typedef uint32_t __attribute__((address_space(3)))*       lptr_t;

__device__ __forceinline__ unsigned short f2bf(float x) {
  union { float f; uint32_t u; } c; c.f = x;
  uint32_t u = c.u + 0x7fffu + ((c.u >> 16) & 1u);   // RNE
  return (unsigned short)(u >> 16);
}

// fp32 -> bf16 with the scale folded in: (1/T) * sqrt(log2(e)),
// so the MFMA accumulator equals a*log2(e), ready for v_exp_f32 (exp2).
__global__ __launch_bounds__(256) void prep_kernel(const float* __restrict__ z,
                                                   unsigned short* __restrict__ zs,
                                                   float* __restrict__ s) {
  const float SC = 12.011224087864498f;  // 10 * sqrt(1.4426950408889634)
  int t = blockIdx.x * 256 + threadIdx.x;
  float4 v = reinterpret_cast<const float4*>(z)[t];
  ushort4 o;
  o.x = f2bf(v.x * SC); o.y = f2bf(v.y * SC);
  o.z = f2bf(v.z * SC); o.w = f2bf(v.w * SC);
  reinterpret_cast<ushort4*>(zs)[t] = o;
  if (t < NROW) s[t] = 0.0f;             // rowsum accumulator (ws is poisoned)
}

// Upper-triangle 256x256 tiles: block (bi,bj), bi<=bj. Off-diagonal tiles add
// rowsums to rows of tile bi AND colsums (== transposed rowsums, by symmetry
// of exp(zs zs^T)) to rows of tile bj. Diagonal: full tile, rowsums only.
// Round-1 proven codegen: 256 threads, wave owns 64 rows, NO forced occupancy
// (round-2 lesson: __launch_bounds__(512,4) -> spills -> 300 MB scratch traffic).
__global__ __launch_bounds__(256, 2) void gemm_exp_kernel(const unsigned short* __restrict__ zs,
                                                          float* __restrict__ s) {
  __shared__ __align__(16) char smem[2 * NB * ROWB + 4 * 256 * 4];  // 32 KB dbuf + 4 KB csm
  float* csm = (float*)(smem + 2 * NB * ROWB);   // [4 waves][256 cols]
  const int tid  = threadIdx.x;
  const int lane = tid & 63;
  const int wid  = tid >> 6;

  // linear block id -> (bi, bj) upper triangle, cum(i) = 64i - i(i-1)/2
  const int t = blockIdx.x;
#define CUM(i) (64 * (i) - ((i) * ((i) - 1)) / 2)
  int bi = (int)((129.0f - sqrtf((float)(16641 - 8 * t))) * 0.5f);
  while (CUM(bi + 1) <= t) ++bi;
  while (CUM(bi) > t) --bi;
  const int bj = bi + (t - CUM(bi));
  const bool isDiag = (bi == bj);
#undef CUM

  const int rowBase = bi * TS + wid * 64;   // this wave's 64 rows
  const int colBase = bj * TS;
  const char* zb = (const char*)zs;

  // A fragments: 16x16x32 A layout row=lane&15, k=(lane>>4)*8+e -> 16B/lane
  bf16x8 afrag[4][4];   // [mf][ks]
  {
    const int r0 = rowBase + (lane & 15);
    const int kb = (lane >> 4) << 4;
#pragma unroll
    for (int mf = 0; mf < 4; ++mf)
#pragma unroll
      for (int ks = 0; ks < 4; ++ks) {
        i32x4 raw = *reinterpret_cast<const i32x4*>(
            zb + (size_t)(r0 + mf * 16) * ROWB + ks * 64 + kb);
        afrag[mf][ks] = __builtin_bit_cast(bf16x8, raw);
      }
  }

  float rs[4][4];   // rowsum accumulators
  float cs[4];      // colsum accumulators [nf], flushed to LDS each j-tile
#pragma unroll
  for (int mf = 0; mf < 4; ++mf)
#pragma unroll
    for (int r = 0; r < 4; ++r) rs[mf][r] = 0.0f;
#pragma unroll
  for (int nf = 0; nf < 4; ++nf) cs[nf] = 0.0f;

  // Stage one 64x128 bf16 B-tile (16 KB): linear LDS dest + inverse-XOR-
  // swizzled global source; reads apply the same involution (rule #21).
#define STAGE_B(buf, jtile)                                                      \
  {                                                                              \
    _Pragma("unroll")                                                            \
    for (int i_ = 0; i_ < 4; ++i_) {                                             \
      const int destByte_ = wid * 4096 + i_ * 1024 + lane * 16;                  \
      const int r_  = destByte_ >> 8;                                            \
      const int cb_ = destByte_ & 0xF0;                                          \
      const int srcByte_ = (colBase + (jtile) * NB + r_) * ROWB                  \
                           + (cb_ ^ ((r_ & 7) << 4));                            \
      __builtin_amdgcn_global_load_lds((gptr_t)(zb + srcByte_),                  \
          (lptr_t)(smem + (buf) * (NB * ROWB) + destByte_), 16, 0, 0);           \
    }                                                                            \
  }

  STAGE_B(0, 0);

#pragma unroll
  for (int jt = 0; jt < JT; ++jt) {
    const int cur = jt & 1;
    if (jt + 1 < JT) {
      STAGE_B(cur ^ 1, jt + 1);
      asm volatile("s_waitcnt vmcnt(4)" ::: "memory");  // current tile landed
    } else {
      asm volatile("s_waitcnt vmcnt(0)" ::: "memory");
    }
    __builtin_amdgcn_s_barrier();

    f32x4 acc[4][4];
#pragma unroll
    for (int mf = 0; mf < 4; ++mf)
#pragma unroll
      for (int nf = 0; nf < 4; ++nf) {
        f32x4 zv = {0.f, 0.f, 0.f, 0.f};
        acc[mf][nf] = zv;
      }

    const char* bufp = smem + cur * (NB * ROWB);
#pragma unroll
    for (int ks = 0; ks < 4; ++ks) {
      bf16x8 bfrag[4];
#pragma unroll
      for (int nf = 0; nf < 4; ++nf) {
        const int r   = nf * 16 + (lane & 15);
        const int kb  = ks * 64 + ((lane >> 4) << 4);
        const int off = r * ROWB + (kb ^ ((r & 7) << 4));
        i32x4 raw = *reinterpret_cast<const i32x4*>(bufp + off);
        bfrag[nf] = __builtin_bit_cast(bf16x8, raw);
      }
#pragma unroll
      for (int mf = 0; mf < 4; ++mf)
#pragma unroll
        for (int nf = 0; nf < 4; ++nf)
          acc[mf][nf] = __builtin_amdgcn_mfma_f32_16x16x32_bf16(
              afrag[mf][ks], bfrag[nf], acc[mf][nf], 0, 0, 0);
    }

    // acc holds a*log2(e) -> exp(a) = exp2(acc); feed row + col accumulators
#pragma unroll
    for (int mf = 0; mf < 4; ++mf)
#pragma unroll
      for (int nf = 0; nf < 4; ++nf) {
        f32x4 a4 = acc[mf][nf];
        float e0 = __builtin_amdgcn_exp2f(a4[0]);
        float e1 = __builtin_amdgcn_exp2f(a4[1]);
        float e2 = __builtin_amdgcn_exp2f(a4[2]);
        float e3 = __builtin_amdgcn_exp2f(a4[3]);
        rs[mf][0] += e0; rs[mf][1] += e1; rs[mf][2] += e2; rs[mf][3] += e3;
        cs[nf] += (e0 + e1) + (e2 + e3);
      }

    // Flush colsum partials for this j-tile: reduce the 4 hi-groups, park in
    // csm (per-wave slice, no cross-wave race), free the registers.
#pragma unroll
    for (int nf = 0; nf < 4; ++nf) {
      float v = cs[nf];
      v += __shfl_xor(v, 16);
      v += __shfl_xor(v, 32);
      if (lane < 16) csm[wid * 256 + jt * 64 + nf * 16 + lane] = v;
      cs[nf] = 0.0f;
    }

    __builtin_amdgcn_s_barrier();   // all waves done reading buf[cur]
  }
#undef STAGE_B

  // Rowsums: C/D layout col=lane&15, row=(lane>>4)*4+reg. Reduce the 16
  // column-lanes, one atomicAdd per row.
#pragma unroll
  for (int mf = 0; mf < 4; ++mf)
#pragma unroll
    for (int r = 0; r < 4; ++r) {
      float v = rs[mf][r];
      v += __shfl_xor(v, 1);
      v += __shfl_xor(v, 2);
      v += __shfl_xor(v, 4);
      v += __shfl_xor(v, 8);
      if ((lane & 15) == 0) {
        const int row = rowBase + mf * 16 + ((lane >> 4) << 2) + r;
        atomicAdd(&s[row], v);
      }
    }

  // Colsums (off-diagonal only): combine the 4 per-wave slabs, one atomic
  // per column. __syncthreads drains the ds_writes (raw s_barrier wouldn't).
  if (!isDiag) {
    __syncthreads();
    float sum = csm[tid] + csm[256 + tid] + csm[512 + tid] + csm[768 + tid];
    atomicAdd(&s[colBase + tid], sum);
  }
}

__global__ __launch_bounds__(1024) void reduce_kernel(const float* __restrict__ s,
                                                      float* __restrict__ out) {
  const int tid = threadIdx.x;
  float acc = 0.0f;
  for (int i = tid; i < NROW; i += 1024) acc += __log2f(s[i]);
#pragma unroll
  for (int m = 32; m >= 1; m >>= 1) acc += __shfl_xor(acc, m);
  __shared__ float wsum[16];
  if ((tid & 63) == 0) wsum[tid >> 6] = acc;
  __syncthreads();
  if (tid == 0) {
    float tot = 0.0f;
#pragma unroll
    for (int w = 0; w < 16; ++w) tot += wsum[w];
    // mean(-log(sum/N)) = log N - (ln2/N) * sum(log2 s_i)
    out[0] = logf((float)NROW) - 0.6931471805599453f * tot / (float)NROW;
  }
}

extern "C" void kernel_launch(void* const* d_in, const int* in_sizes, int n_in,
                              void* d_out, int out_size, void* d_ws, size_t ws_size,
                              hipStream_t stream) {
  const float* z = (const float*)d_in[0];
  unsigned short* zs = (unsigned short*)d_ws;                       // 4 MB bf16
  float* s = (float*)((char*)d_ws + (size_t)NROW * DDIM * 2);       // 64 KB rowsums
  float* out = (float*)d_out;

  prep_kernel<<<dim3(NROW * DDIM / 4 / 256), dim3(256), 0, stream>>>(z, zs, s);
  gemm_exp_kernel<<<dim3(NBLK), dim3(256), 0, stream>>>(zs, s);
  reduce_kernel<<<dim3(1), dim3(1024), 0, stream>>>(s, out);
}

// Round 4
// 82.272 us; speedup vs baseline: 2.3578x; 1.9808x over previous
//
#include <hip/hip_runtime.h>
#include <stdint.h>

#define NROW 16384
#define DDIM 128
#define ROWB 256            // bytes per row of bf16 z

constexpr int TS    = 256;                      // square tile side
constexpr int NTILE = NROW / TS;                // 64
constexpr int NBLK  = NTILE * (NTILE + 1) / 2;  // 2080 upper-tri tiles
constexpr int NB    = 64;                       // cols per j-tile
constexpr int JT    = TS / NB;                  // 4 j-tiles per block

typedef __bf16 bf16x8 __attribute__((ext_vector_type(8)));
typedef float  f32x4  __attribute__((ext_vector_type(4)));
typedef int    i32x4  __attribute__((ext_vector_type(4)));

typedef const uint32_t __attribute__((address_space(1)))* gptr_t;
typedef uint32_t __attribute__((address_space(3)))*       lptr_t;

__device__ __forceinline__ unsigned short f2bf(float x) {
  union { float f; uint32_t u; } c; c.f = x;
  uint32_t u = c.u + 0x7fffu + ((c.u >> 16) & 1u);   // RNE
  return (unsigned short)(u >> 16);
}

// fp32 -> bf16 with the scale folded in: (1/T) * sqrt(log2(e)),
// so the MFMA accumulator equals a*log2(e), ready for v_exp_f32 (exp2).
__global__ __launch_bounds__(256) void prep_kernel(const float* __restrict__ z,
                                                   unsigned short* __restrict__ zs,
                                                   float* __restrict__ s) {
  const float SC = 12.011224087864498f;  // 10 * sqrt(1.4426950408889634)
  int t = blockIdx.x * 256 + threadIdx.x;
  float4 v = reinterpret_cast<const float4*>(z)[t];
  ushort4 o;
  o.x = f2bf(v.x * SC); o.y = f2bf(v.y * SC);
  o.z = f2bf(v.z * SC); o.w = f2bf(v.w * SC);
  reinterpret_cast<ushort4*>(zs)[t] = o;
  if (t < NROW) s[t] = 0.0f;             // rowsum accumulator (ws is poisoned)
}

// Upper-triangle 256x256 tiles: block (bi,bj), bi<=bj. Off-diagonal tiles add
// rowsums to rows of tile bi AND colsums (== transposed rowsums, by symmetry
// of exp(zs zs^T)) to rows of tile bj. Diagonal: full tile, rowsums only.
//
// Round-2 lesson: never force occupancy past live state (spill -> 300 MB
// scratch traffic). Round-3 lesson: the fully-unrolled JT=4 loop pipelines
// 4 iterations together and spills the same way -> keep the jt loop ROLLED
// (round-1 proven codegen: rolled loop, 92 VGPR, zero spill).
__global__ __launch_bounds__(256, 2) void gemm_exp_kernel(const unsigned short* __restrict__ zs,
                                                          float* __restrict__ s) {
  __shared__ __align__(16) char smem[2 * NB * ROWB + 4 * 256 * 4];  // 32 KB dbuf + 4 KB csm
  float* csm = (float*)(smem + 2 * NB * ROWB);   // [4 waves][256 cols]
  const int tid  = threadIdx.x;
  const int lane = tid & 63;
  const int wid  = tid >> 6;

  // linear block id -> (bi, bj) upper triangle, cum(i) = 64i - i(i-1)/2
  const int t = blockIdx.x;
#define CUM(i) (64 * (i) - ((i) * ((i) - 1)) / 2)
  int bi = (int)((129.0f - sqrtf((float)(16641 - 8 * t))) * 0.5f);
  while (CUM(bi + 1) <= t) ++bi;
  while (CUM(bi) > t) --bi;
  const int bj = bi + (t - CUM(bi));
  const bool isDiag = (bi == bj);
#undef CUM

  const int rowBase = bi * TS + wid * 64;   // this wave's 64 rows
  const int colBase = bj * TS;
  const char* zb = (const char*)zs;

  // A fragments: 16x16x32 A layout row=lane&15, k=(lane>>4)*8+e -> 16B/lane
  bf16x8 afrag[4][4];   // [mf][ks]
  {
    const int r0 = rowBase + (lane & 15);
    const int kb = (lane >> 4) << 4;
#pragma unroll
    for (int mf = 0; mf < 4; ++mf)
#pragma unroll
      for (int ks = 0; ks < 4; ++ks) {
        i32x4 raw = *reinterpret_cast<const i32x4*>(
            zb + (size_t)(r0 + mf * 16) * ROWB + ks * 64 + kb);
        afrag[mf][ks] = __builtin_bit_cast(bf16x8, raw);
      }
  }

  float rs[4][4];   // rowsum accumulators
  float cs[4];      // colsum accumulators [nf], flushed to LDS each j-tile
#pragma unroll
  for (int mf = 0; mf < 4; ++mf)
#pragma unroll
    for (int r = 0; r < 4; ++r) rs[mf][r] = 0.0f;
#pragma unroll
  for (int nf = 0; nf < 4; ++nf) cs[nf] = 0.0f;

  // Stage one 64x128 bf16 B-tile (16 KB): linear LDS dest + inverse-XOR-
  // swizzled global source; reads apply the same involution (rule #21).
#define STAGE_B(buf, jtile)                                                      \
  {                                                                              \
    _Pragma("unroll")                                                            \
    for (int i_ = 0; i_ < 4; ++i_) {                                             \
      const int destByte_ = wid * 4096 + i_ * 1024 + lane * 16;                  \
      const int r_  = destByte_ >> 8;                                            \
      const int cb_ = destByte_ & 0xF0;                                          \
      const int srcByte_ = (colBase + (jtile) * NB + r_) * ROWB                  \
                           + (cb_ ^ ((r_ & 7) << 4));                            \
      __builtin_amdgcn_global_load_lds((gptr_t)(zb + srcByte_),                  \
          (lptr_t)(smem + (buf) * (NB * ROWB) + destByte_), 16, 0, 0);           \
    }                                                                            \
  }

  STAGE_B(0, 0);

#pragma unroll 1   // KEEP ROLLED: full unroll spills (round-3 post-mortem)
  for (int jt = 0; jt < JT; ++jt) {
    const int cur = jt & 1;
    if (jt + 1 < JT) {
      STAGE_B(cur ^ 1, jt + 1);
      asm volatile("s_waitcnt vmcnt(4)" ::: "memory");  // current tile landed
    } else {
      asm volatile("s_waitcnt vmcnt(0)" ::: "memory");
    }
    __builtin_amdgcn_s_barrier();

    f32x4 acc[4][4];
#pragma unroll
    for (int mf = 0; mf < 4; ++mf)
#pragma unroll
      for (int nf = 0; nf < 4; ++nf) {
        f32x4 zv = {0.f, 0.f, 0.f, 0.f};
        acc[mf][nf] = zv;
      }

    const char* bufp = smem + cur * (NB * ROWB);
#pragma unroll
    for (int ks = 0; ks < 4; ++ks) {
      bf16x8 bfrag[4];
#pragma unroll
      for (int nf = 0; nf < 4; ++nf) {
        const int r   = nf * 16 + (lane & 15);
        const int kb  = ks * 64 + ((lane >> 4) << 4);
        const int off = r * ROWB + (kb ^ ((r & 7) << 4));
        i32x4 raw = *reinterpret_cast<const i32x4*>(bufp + off);
        bfrag[nf] = __builtin_bit_cast(bf16x8, raw);
      }
#pragma unroll
      for (int mf = 0; mf < 4; ++mf)
#pragma unroll
        for (int nf = 0; nf < 4; ++nf)
          acc[mf][nf] = __builtin_amdgcn_mfma_f32_16x16x32_bf16(
              afrag[mf][ks], bfrag[nf], acc[mf][nf], 0, 0, 0);
    }

    // acc holds a*log2(e) -> exp(a) = exp2(acc); feed row + col accumulators
#pragma unroll
    for (int mf = 0; mf < 4; ++mf)
#pragma unroll
      for (int nf = 0; nf < 4; ++nf) {
        f32x4 a4 = acc[mf][nf];
        float e0 = __builtin_amdgcn_exp2f(a4[0]);
        float e1 = __builtin_amdgcn_exp2f(a4[1]);
        float e2 = __builtin_amdgcn_exp2f(a4[2]);
        float e3 = __builtin_amdgcn_exp2f(a4[3]);
        rs[mf][0] += e0; rs[mf][1] += e1; rs[mf][2] += e2; rs[mf][3] += e3;
        cs[nf] += (e0 + e1) + (e2 + e3);
      }

    // Flush colsum partials for this j-tile: reduce the 4 hi-groups, park in
    // csm (per-wave slice, no cross-wave race), free the registers.
#pragma unroll
    for (int nf = 0; nf < 4; ++nf) {
      float v = cs[nf];
      v += __shfl_xor(v, 16);
      v += __shfl_xor(v, 32);
      if (lane < 16) csm[wid * 256 + jt * 64 + nf * 16 + lane] = v;
      cs[nf] = 0.0f;
    }

    __builtin_amdgcn_s_barrier();   // all waves done reading buf[cur]
  }
#undef STAGE_B

  // Rowsums: C/D layout col=lane&15, row=(lane>>4)*4+reg. Reduce the 16
  // column-lanes, one atomicAdd per row.
#pragma unroll
  for (int mf = 0; mf < 4; ++mf)
#pragma unroll
    for (int r = 0; r < 4; ++r) {
      float v = rs[mf][r];
      v += __shfl_xor(v, 1);
      v += __shfl_xor(v, 2);
      v += __shfl_xor(v, 4);
      v += __shfl_xor(v, 8);
      if ((lane & 15) == 0) {
        const int row = rowBase + mf * 16 + ((lane >> 4) << 2) + r;
        atomicAdd(&s[row], v);
      }
    }

  // Colsums (off-diagonal only): combine the 4 per-wave slabs, one atomic
  // per column. __syncthreads drains the ds_writes (raw s_barrier wouldn't).
  if (!isDiag) {
    __syncthreads();
    float sum = csm[tid] + csm[256 + tid] + csm[512 + tid] + csm[768 + tid];
    atomicAdd(&s[colBase + tid], sum);
  }
}

__global__ __launch_bounds__(1024) void reduce_kernel(const float* __restrict__ s,
                                                      float* __restrict__ out) {
  const int tid = threadIdx.x;
  float acc = 0.0f;
  for (int i = tid; i < NROW; i += 1024) acc += __log2f(s[i]);
#pragma unroll
  for (int m = 32; m >= 1; m >>= 1) acc += __shfl_xor(acc, m);
  __shared__ float wsum[16];
  if ((tid & 63) == 0) wsum[tid >> 6] = acc;
  __syncthreads();
  if (tid == 0) {
    float tot = 0.0f;
#pragma unroll
    for (int w = 0; w < 16; ++w) tot += wsum[w];
    // mean(-log(sum/N)) = log N - (ln2/N) * sum(log2 s_i)
    out[0] = logf((float)NROW) - 0.6931471805599453f * tot / (float)NROW;
  }
}

extern "C" void kernel_launch(void* const* d_in, const int* in_sizes, int n_in,
                              void* d_out, int out_size, void* d_ws, size_t ws_size,
                              hipStream_t stream) {
  const float* z = (const float*)d_in[0];
  unsigned short* zs = (unsigned short*)d_ws;                       // 4 MB bf16
  float* s = (float*)((char*)d_ws + (size_t)NROW * DDIM * 2);       // 64 KB rowsums
  float* out = (float*)d_out;

  prep_kernel<<<dim3(NROW * DDIM / 4 / 256), dim3(256), 0, stream>>>(z, zs, s);
  gemm_exp_kernel<<<dim3(NBLK), dim3(256), 0, stream>>>(zs, s);
  reduce_kernel<<<dim3(1), dim3(1024), 0, stream>>>(s, out);
}